// Round 7
// baseline (65.398 us; speedup 1.0000x reference)
//
#include <hip/hip_runtime.h>
#include <math.h>

#define IN_SIZE 448
#define OUT_SIZE 224
#define JPT 4                       // output columns per thread

typedef float floatx4 __attribute__((ext_vector_type(4)));  // native vector: OK for nontemporal builtin

// jax.nn.sigmoid(10*d) at INTEGER d, branchless 5-case select.
// Exact f32 for |d|<=1; abs error < 2.1e-9 elsewhere.
__device__ __forceinline__ float sig10i(int d) {
    const float neg = (d == -1) ? 4.5397868e-5f : 2.0611536e-9f;
    const float pos = (d == 0) ? 0.5f : ((d == 1) ? 0.99995458f : 1.0f);
    return (d < 0) ? neg : pos;
}

__global__ __launch_bounds__(256) void attention_crop_kernel(
    const float* __restrict__ images,   // [B,3,448,448]
    const float* __restrict__ locs,     // [B,3]
    float* __restrict__ out)            // [B,3,224,224]
{
    // XCD chunk swizzle: each XCD gets a contiguous chunk of samples
    // (per-sample 2.4 MB fits the 4 MB per-XCD L2). grid % 8 == 0.
    const int cpx = gridDim.x >> 3;
    const int bid = (blockIdx.x & 7) * cpx + (blockIdx.x >> 3);

    // thread -> (b, i, j0): 56 j-groups per row; 12544 threads per sample (49 blocks)
    const int idx = bid * 256 + threadIdx.x;
    const int b   = idx / (OUT_SIZE * (OUT_SIZE / JPT));
    const int rem = idx - b * (OUT_SIZE * (OUT_SIZE / JPT));
    const int i   = rem / (OUT_SIZE / JPT);
    const int jg  = rem - i * (OUT_SIZE / JPT);
    const int j0  = jg * JPT;

    // ---- per-sample scalars (wave-uniform) ----
    float tx = locs[b * 3 + 0];
    float ty = locs[b * 3 + 1];
    float tl = locs[b * 3 + 2];
    const float third = 448.0f / 3.0f;
    tl = fmaxf(tl, third);
    tx = fminf(fmaxf(tx, tl), 448.0f - tl);
    ty = fminf(fmaxf(ty, tl), 448.0f - tl);

    const float w_off_f = fminf(fmaxf(floorf(tx - tl), 0.0f), 448.0f);
    const float h_off_f = fminf(fmaxf(floorf(ty - tl), 0.0f), 448.0f);
    const float w_end_f = fminf(fmaxf(floorf(tx + tl), 0.0f), 448.0f);
    const float h_end_f = fminf(fmaxf(floorf(ty + tl), 0.0f), 448.0f);
    const int w_off = (int)w_off_f;
    const int h_off = (int)h_off_f;
    const int w_end = (int)w_end_f;
    const int h_end = (int)h_end_f;
    const float rspan = (float)(w_end - 1 - w_off);
    const float cspan = (float)(h_end - 1 - h_off);

    // ---- row coordinate: shared across the 4 output columns ----
    const float r   = w_off_f + ((float)i / 223.0f) * rspan;
    const float r0f = floorf(r);
    const int   r0  = (int)r0f;
    const int   r1  = min(r0 + 1, IN_SIZE - 1);
    const float fr  = r - r0f;
    const float mr0 = sig10i(r0 - w_off) - sig10i(r0 - w_end);
    const float mr1 = sig10i(r1 - w_off) - sig10i(r1 - w_end);

    // ---- column coordinates/masks for the 4 j's ----
    int   c0[JPT], c1[JPT];
    float fc[JPT], mc0[JPT], mc1[JPT];
#pragma unroll
    for (int k = 0; k < JPT; ++k) {
        const float c   = h_off_f + ((float)(j0 + k) / 223.0f) * cspan;
        const float c0f = floorf(c);
        c0[k] = (int)c0f;
        c1[k] = min(c0[k] + 1, IN_SIZE - 1);
        fc[k] = c - c0f;
        mc0[k] = sig10i(c0[k] - h_off) - sig10i(c0[k] - h_end);
        mc1[k] = sig10i(c1[k] - h_off) - sig10i(c1[k] - h_end);
    }

    const size_t img_base = (size_t)b * 3 * IN_SIZE * IN_SIZE;
    const size_t out_base = (size_t)b * 3 * OUT_SIZE * OUT_SIZE
                          + (size_t)i * OUT_SIZE + j0;
    const int row0 = r0 * IN_SIZE;
    const int row1 = r1 * IN_SIZE;

#pragma unroll
    for (int ch = 0; ch < 3; ++ch) {
        const float* __restrict__ img = images + img_base + (size_t)ch * IN_SIZE * IN_SIZE;
        floatx4 res;
#pragma unroll
        for (int k = 0; k < JPT; ++k) {
            const float v00 = img[row0 + c0[k]] * (mr0 * mc0[k]);
            const float v01 = img[row0 + c1[k]] * (mr0 * mc1[k]);
            const float v10 = img[row1 + c0[k]] * (mr1 * mc0[k]);
            const float v11 = img[row1 + c1[k]] * (mr1 * mc1[k]);
            const float top = v00 * (1.0f - fc[k]) + v01 * fc[k];
            const float bot = v10 * (1.0f - fc[k]) + v11 * fc[k];
            res[k] = top * (1.0f - fr) + bot * fr;
        }
        // streaming 16B store: coalesced, and don't evict L3-resident input
        __builtin_nontemporal_store(res,
            (floatx4*)&out[out_base + (size_t)ch * OUT_SIZE * OUT_SIZE]);
    }
}

extern "C" void kernel_launch(void* const* d_in, const int* in_sizes, int n_in,
                              void* d_out, int out_size, void* d_ws, size_t ws_size,
                              hipStream_t stream) {
    const float* images = (const float*)d_in[0];   // [64,3,448,448] f32
    const float* locs   = (const float*)d_in[1];   // [64,3] f32
    float* out = (float*)d_out;                    // [64,3,224,224] f32

    const int B = in_sizes[1] / 3;                            // 64
    const int total = B * OUT_SIZE * (OUT_SIZE / JPT);        // 802816 threads
    const int block = 256;
    const int grid = (total + block - 1) / block;             // 3136 (div by 8)
    attention_crop_kernel<<<grid, block, 0, stream>>>(images, locs, out);
}

// Round 8
// 40.321 us; speedup vs baseline: 1.6219x; 1.6219x over previous
//
#include <hip/hip_runtime.h>
#include <math.h>

#define IN_SIZE 448
#define OUT_SIZE 224
#define IPT 4                       // output ROWS per thread (lanes stay consecutive in j!)

// jax.nn.sigmoid(10*d) at INTEGER d, branchless 5-case select.
// Exact f32 for |d|<=1; abs error < 2.1e-9 elsewhere.
__device__ __forceinline__ float sig10i(int d) {
    const float neg = (d == -1) ? 4.5397868e-5f : 2.0611536e-9f;
    const float pos = (d == 0) ? 0.5f : ((d == 1) ? 0.99995458f : 1.0f);
    return (d < 0) ? neg : pos;
}

__global__ __launch_bounds__(256) void attention_crop_kernel(
    const float* __restrict__ images,   // [B,3,448,448]
    const float* __restrict__ locs,     // [B,3]
    float* __restrict__ out)            // [B,3,224,224]
{
    // XCD chunk swizzle: each XCD gets a contiguous chunk of samples
    // (per-sample 2.4 MB fits the 4 MB per-XCD L2). grid % 8 == 0.
    const int cpx = gridDim.x >> 3;
    const int bid = (blockIdx.x & 7) * cpx + (blockIdx.x >> 3);

    // thread -> (b, i0, j); j is the FASTEST dim so consecutive lanes read
    // consecutive input columns (round-3 coalescing, round-7's mistake undone).
    const int idx = bid * 256 + threadIdx.x;
    const int j   = idx % OUT_SIZE;
    const int t   = idx / OUT_SIZE;
    const int ig  = t % (OUT_SIZE / IPT);
    const int b   = t / (OUT_SIZE / IPT);
    const int i0  = ig * IPT;

    // ---- per-sample scalars (wave-uniform) ----
    float tx = locs[b * 3 + 0];
    float ty = locs[b * 3 + 1];
    float tl = locs[b * 3 + 2];
    const float third = 448.0f / 3.0f;
    tl = fmaxf(tl, third);
    tx = fminf(fmaxf(tx, tl), 448.0f - tl);
    ty = fminf(fmaxf(ty, tl), 448.0f - tl);

    const float w_off_f = fminf(fmaxf(floorf(tx - tl), 0.0f), 448.0f);
    const float h_off_f = fminf(fmaxf(floorf(ty - tl), 0.0f), 448.0f);
    const float w_end_f = fminf(fmaxf(floorf(tx + tl), 0.0f), 448.0f);
    const float h_end_f = fminf(fmaxf(floorf(ty + tl), 0.0f), 448.0f);
    const int w_off = (int)w_off_f;
    const int h_off = (int)h_off_f;
    const int w_end = (int)w_end_f;
    const int h_end = (int)h_end_f;
    const float rspan = (float)(w_end - 1 - w_off);
    const float cspan = (float)(h_end - 1 - h_off);

    // ---- column coordinate/mask: computed ONCE, shared by the 4 rows ----
    const float c   = h_off_f + ((float)j / 223.0f) * cspan;
    const float c0f = floorf(c);
    const int   c0  = (int)c0f;
    const int   c1  = min(c0 + 1, IN_SIZE - 1);
    const float fc  = c - c0f;
    const float mc0 = sig10i(c0 - h_off) - sig10i(c0 - h_end);
    const float mc1 = sig10i(c1 - h_off) - sig10i(c1 - h_end);

    // ---- row coordinates/masks for the 4 rows ----
    int   row0[IPT], row1[IPT];
    float fr[IPT], mr0[IPT], mr1[IPT];
#pragma unroll
    for (int k = 0; k < IPT; ++k) {
        const float r   = w_off_f + ((float)(i0 + k) / 223.0f) * rspan;
        const float r0f = floorf(r);
        const int   r0  = (int)r0f;
        const int   r1  = min(r0 + 1, IN_SIZE - 1);
        fr[k]   = r - r0f;
        mr0[k]  = sig10i(r0 - w_off) - sig10i(r0 - w_end);
        mr1[k]  = sig10i(r1 - w_off) - sig10i(r1 - w_end);
        row0[k] = r0 * IN_SIZE;
        row1[k] = r1 * IN_SIZE;
    }

    const size_t img_base = (size_t)b * 3 * IN_SIZE * IN_SIZE;
    const size_t out_base = (size_t)b * 3 * OUT_SIZE * OUT_SIZE
                          + (size_t)i0 * OUT_SIZE + j;

#pragma unroll
    for (int ch = 0; ch < 3; ++ch) {
        const float* __restrict__ img = images + img_base + (size_t)ch * IN_SIZE * IN_SIZE;
        float* __restrict__ op = out + out_base + (size_t)ch * OUT_SIZE * OUT_SIZE;
#pragma unroll
        for (int k = 0; k < IPT; ++k) {
            const float v00 = img[row0[k] + c0] * (mr0[k] * mc0);
            const float v01 = img[row0[k] + c1] * (mr0[k] * mc1);
            const float v10 = img[row1[k] + c0] * (mr1[k] * mc0);
            const float v11 = img[row1[k] + c1] * (mr1[k] * mc1);
            const float top = v00 * (1.0f - fc) + v01 * fc;
            const float bot = v10 * (1.0f - fc) + v11 * fc;
            const float res = top * (1.0f - fr[k]) + bot * fr[k];
            // streaming scalar store: coalesced across lanes (consecutive j)
            __builtin_nontemporal_store(res, op + (size_t)k * OUT_SIZE);
        }
    }
}

extern "C" void kernel_launch(void* const* d_in, const int* in_sizes, int n_in,
                              void* d_out, int out_size, void* d_ws, size_t ws_size,
                              hipStream_t stream) {
    const float* images = (const float*)d_in[0];   // [64,3,448,448] f32
    const float* locs   = (const float*)d_in[1];   // [64,3] f32
    float* out = (float*)d_out;                    // [64,3,224,224] f32

    const int B = in_sizes[1] / 3;                            // 64
    const int total = B * (OUT_SIZE / IPT) * OUT_SIZE;        // 802816 threads
    const int block = 256;
    const int grid = (total + block - 1) / block;             // 3136 (div by 8)
    attention_crop_kernel<<<grid, block, 0, stream>>>(images, locs, out);
}

// Round 9
// 29.167 us; speedup vs baseline: 2.2422x; 1.3824x over previous
//
#include <hip/hip_runtime.h>
#include <math.h>

#define IN_SIZE 448
#define OUT_SIZE 224
#define PLANE (IN_SIZE * IN_SIZE)

// jax.nn.sigmoid(10*d) at INTEGER d, branchless 5-case select.
// Exact f32 for |d|<=1; abs error < 2.1e-9 elsewhere.
__device__ __forceinline__ float sig10i(int d) {
    const float neg = (d == -1) ? 4.5397868e-5f : 2.0611536e-9f;
    const float pos = (d == 0) ? 0.5f : ((d == 1) ? 0.99995458f : 1.0f);
    return (d < 0) ? neg : pos;
}

__global__ __launch_bounds__(256) void attention_crop_kernel(
    const float* __restrict__ images,   // [B,3,448,448]
    const float* __restrict__ locs,     // [B,3]
    float* __restrict__ out)            // [B,3,224,224]
{
    // XCD chunk swizzle: each XCD gets a contiguous chunk of samples
    // (per-sample 2.4 MB fits the 4 MB per-XCD L2). grid % 8 == 0.
    const int cpx = gridDim.x >> 3;
    const int bid = (blockIdx.x & 7) * cpx + (blockIdx.x >> 3);

    // 1 output pixel per thread (3 channels) — max thread count = max MLP.
    const int idx = bid * 256 + threadIdx.x;
    const int b   = idx / (OUT_SIZE * OUT_SIZE);
    const int rem = idx - b * (OUT_SIZE * OUT_SIZE);
    const int i   = rem / OUT_SIZE;
    const int j   = rem - i * OUT_SIZE;

    // ---- per-sample scalars (wave-uniform) ----
    float tx = locs[b * 3 + 0];
    float ty = locs[b * 3 + 1];
    float tl = locs[b * 3 + 2];
    const float third = 448.0f / 3.0f;
    tl = fmaxf(tl, third);
    tx = fminf(fmaxf(tx, tl), 448.0f - tl);
    ty = fminf(fmaxf(ty, tl), 448.0f - tl);

    const float w_off_f = fminf(fmaxf(floorf(tx - tl), 0.0f), 448.0f);
    const float h_off_f = fminf(fmaxf(floorf(ty - tl), 0.0f), 448.0f);
    const float w_end_f = fminf(fmaxf(floorf(tx + tl), 0.0f), 448.0f);
    const float h_end_f = fminf(fmaxf(floorf(ty + tl), 0.0f), 448.0f);
    const int w_off = (int)w_off_f;
    const int h_off = (int)h_off_f;
    const int w_end = (int)w_end_f;
    const int h_end = (int)h_end_f;

    // ---- sample coords; clamp-refactor so r1=r0+1, c1=c0+1 ALWAYS ----
    // (identical math: when floor hits 447 the old fc/fr was 0 and the new
    //  weights (1-f)=0, f=1 select the same tap·mask term)
    const float r = w_off_f + ((float)i / 223.0f) * (float)(w_end - 1 - w_off);
    const float c = h_off_f + ((float)j / 223.0f) * (float)(h_end - 1 - h_off);
    const int r0 = min((int)floorf(r), IN_SIZE - 2);
    const int c0 = min((int)floorf(c), IN_SIZE - 2);
    const float fr = r - (float)r0;
    const float fc = c - (float)c0;

    // ---- masks at the 4 taps (LUT) ----
    const float mr0 = sig10i(r0 - w_off)     - sig10i(r0 - w_end);
    const float mr1 = sig10i(r0 + 1 - w_off) - sig10i(r0 + 1 - w_end);
    const float mc0 = sig10i(c0 - h_off)     - sig10i(c0 - h_end);
    const float mc1 = sig10i(c0 + 1 - h_off) - sig10i(c0 + 1 - h_end);

    // ---- combined weight per tap (mask × bilinear), shared by 3 channels ----
    const float W00 = mr0 * mc0 * (1.0f - fc) * (1.0f - fr);
    const float W01 = mr0 * mc1 * fc * (1.0f - fr);
    const float W10 = mr1 * mc0 * (1.0f - fc) * fr;
    const float W11 = mr1 * mc1 * fc * fr;

    const size_t img_base = (size_t)b * 3 * PLANE + (size_t)r0 * IN_SIZE + c0;
    const size_t out_base = (size_t)b * 3 * OUT_SIZE * OUT_SIZE
                          + (size_t)i * OUT_SIZE + j;

#pragma unroll
    for (int ch = 0; ch < 3; ++ch) {
        const float* __restrict__ p = images + img_base + (size_t)ch * PLANE;
        float t[2], bt[2];                       // (v00,v01) and (v10,v11): adjacent pairs
        __builtin_memcpy(t,  p,           8);    // 8B load, any 4B alignment ok
        __builtin_memcpy(bt, p + IN_SIZE, 8);
        const float res = t[0] * W00 + t[1] * W01 + bt[0] * W10 + bt[1] * W11;
        // streaming store: coalesced across lanes (consecutive j)
        __builtin_nontemporal_store(res, out + out_base + (size_t)ch * OUT_SIZE * OUT_SIZE);
    }
}

extern "C" void kernel_launch(void* const* d_in, const int* in_sizes, int n_in,
                              void* d_out, int out_size, void* d_ws, size_t ws_size,
                              hipStream_t stream) {
    const float* images = (const float*)d_in[0];   // [64,3,448,448] f32
    const float* locs   = (const float*)d_in[1];   // [64,3] f32
    float* out = (float*)d_out;                    // [64,3,224,224] f32

    const int B = in_sizes[1] / 3;                 // 64
    const int total = B * OUT_SIZE * OUT_SIZE;     // 3.2M threads, 1 px each
    const int block = 256;
    const int grid = (total + block - 1) / block;  // 12544 (div by 8)
    attention_crop_kernel<<<grid, block, 0, stream>>>(images, locs, out);
}